// Round 4
// baseline (497.356 us; speedup 1.0000x reference)
//
#include <hip/hip_runtime.h>
#include <hip/hip_bf16.h>
#include <cstdint>
#include <cstddef>

#define BB 8
#define SS 1024
#define DDIM 768
#define FFF 3072
#define EE 8

typedef __attribute__((ext_vector_type(8))) short short8;
typedef __attribute__((ext_vector_type(4))) float f32x4;
typedef __attribute__((ext_vector_type(4))) unsigned short us4;

__device__ __forceinline__ unsigned short f2bf(float f) {
  unsigned u = __float_as_uint(f);
  u += 0x7FFFu + ((u >> 16) & 1u);
  return (unsigned short)(u >> 16);
}

__device__ __forceinline__ void async_ld16(const void* g, void* l) {
  __builtin_amdgcn_global_load_lds(
      (const __attribute__((address_space(1))) void*)g,
      (__attribute__((address_space(3))) void*)l, 16, 0, 0);
}

// ---------------- fused prep: tcast W1 | tcast W2 | cast x | pooled ----------------
__global__ __launch_bounds__(256) void prep_kernel(
    const float* __restrict__ W1, const float* __restrict__ W2,
    const float* __restrict__ x,
    unsigned short* __restrict__ w1t, unsigned short* __restrict__ w2t,
    unsigned short* __restrict__ xb, float* __restrict__ pooled) {
  __shared__ unsigned short tile[64 * 66 + 32];
  int blk = blockIdx.x;
  int t = threadIdx.x;
  if (blk < 9216) {
    const float* src; unsigned short* dst; int R, C, r0, c0;
    if (blk < 4608) {
      int e = blk / 576, rem = blk % 576;           // 12 r-tiles x 48 c-tiles
      r0 = (rem / 48) * 64; c0 = (rem % 48) * 64;
      src = W1 + (size_t)e * DDIM * FFF; dst = w1t + (size_t)e * FFF * DDIM;
      R = DDIM; C = FFF;
    } else {
      int b2 = blk - 4608;
      int e = b2 / 576, rem = b2 % 576;             // 48 r-tiles x 12 c-tiles
      r0 = (rem / 12) * 64; c0 = (rem % 12) * 64;
      src = W2 + (size_t)e * FFF * DDIM; dst = w2t + (size_t)e * DDIM * FFF;
      R = FFF; C = DDIM;
    }
    int row = t >> 4, c4 = (t & 15) * 4;
#pragma unroll
    for (int it = 0; it < 4; it++) {
      int r = row + it * 16;
      float4 v = *(const float4*)&src[(size_t)(r0 + r) * C + c0 + c4];
      us4 u; u[0] = f2bf(v.x); u[1] = f2bf(v.y); u[2] = f2bf(v.z); u[3] = f2bf(v.w);
      *(us4*)&tile[r * 66 + c4] = u;
    }
    __syncthreads();
    int seg = (t & 7) * 8;
#pragma unroll
    for (int it = 0; it < 2; it++) {
      int crow = it * 32 + (t >> 3);
      short8 u;
#pragma unroll
      for (int j = 0; j < 8; j++) u[j] = (short)tile[(seg + j) * 66 + crow];
      *(short8*)&dst[(size_t)(c0 + crow) * R + r0 + seg] = u;
    }
  } else if (blk < 12288) {
    size_t i = ((size_t)(blk - 9216) * 256 + t) * 8;
    float4 a = *(const float4*)&x[i];
    float4 b = *(const float4*)&x[i + 4];
    short8 u;
    u[0] = f2bf(a.x); u[1] = f2bf(a.y); u[2] = f2bf(a.z); u[3] = f2bf(a.w);
    u[4] = f2bf(b.x); u[5] = f2bf(b.y); u[6] = f2bf(b.z); u[7] = f2bf(b.w);
    *(short8*)&xb[i] = u;
  } else {
    float* red = (float*)tile;
    int blk2 = blk - 12288;
    int b = blk2 / 24, d0 = (blk2 % 24) * 32;
    int dl = t & 31, sg = t >> 5;
    const float* p = x + ((size_t)b * SS + sg) * DDIM + d0 + dl;
    float s = 0.f;
#pragma unroll 4
    for (int i = 0; i < SS / 8; i++) s += p[(size_t)i * 8 * DDIM];
    red[t] = s;
    __syncthreads();
    if (t < 32) {
      float acc = red[t];
#pragma unroll
      for (int g = 1; g < 8; g++) acc += red[g * 32 + t];
      pooled[b * DDIM + d0 + t] = acc * (1.f / SS);
    }
  }
}

// ---------------- router ----------------
__global__ void router_kernel(const float* __restrict__ pooled,
                              const float* __restrict__ text,
                              const float* __restrict__ rw,
                              const float* __restrict__ rb,
                              float* __restrict__ probs_out,
                              int* __restrict__ topi,
                              float* __restrict__ topv) {
  __shared__ float lg[BB * EE];
  int t = threadIdx.x;
  int be = t >> 4, part = t & 15;
  int b = be >> 3, e = be & 7;
  const float* pb = pooled + b * DDIM;
  const float* tb = text + b * DDIM;
  float acc = 0.f;
  int i0 = part * 96;
  for (int i = i0; i < i0 + 96; i++) {
    float f = (i < DDIM) ? pb[i] : tb[i - DDIM];
    acc += f * rw[i * EE + e];
  }
#pragma unroll
  for (int o = 8; o >= 1; o >>= 1) acc += __shfl_xor(acc, o);
  if (part == 0) lg[be] = acc + rb[e];
  __syncthreads();
  if (t < BB) {
    float p[EE];
    float mx = -1e30f;
    for (int e2 = 0; e2 < EE; e2++) { p[e2] = lg[t * EE + e2]; mx = fmaxf(mx, p[e2]); }
    float s = 0.f;
    for (int e2 = 0; e2 < EE; e2++) { p[e2] = expf(p[e2] - mx); s += p[e2]; }
    float inv = 1.f / s;
    for (int e2 = 0; e2 < EE; e2++) { p[e2] *= inv; probs_out[t * EE + e2] = p[e2]; }
    int j0 = 0; float v0 = p[0];
    for (int e2 = 1; e2 < EE; e2++) if (p[e2] > v0) { v0 = p[e2]; j0 = e2; }
    int j1 = -1; float v1 = -1e30f;
    for (int e2 = 0; e2 < EE; e2++) if (e2 != j0 && p[e2] > v1) { v1 = p[e2]; j1 = e2; }
    topi[t * 2] = j0; topi[t * 2 + 1] = j1;
    topv[t * 2] = v0; topv[t * 2 + 1] = v1;
  }
}

// ---------------- 192x128 tile GEMM, BK=64, 2 blocks/CU, minimal sync ----------------
// LDS per stage (ush): A 192x64 @0,4096,8192 (3 units); B 128x64 @12288,16384 (2 units).
// Stage stride 20480 ush (40KB); 2 stages = 80KB/block -> exactly 2 blocks/CU (160KB).
// 8 waves (4M x 2N), wave-tile 48x64, acc[3][4] = 48 VGPR.
// Per K-tile: vmcnt(5) -> barrier -> compiler-scheduled {14 ds_read_b128 + 24 MFMA}
// -> barrier -> issue stage kt+2 (5 global_load_lds). Ledger: steady outstanding at
// wait = next stage's 5; last tile vmcnt(0).
// GELU=true: gemm1 (A=w1t rows=FF, B=xb rows=S, LDK=DDIM, NT=12, TPP=128)
// GELU=false: gemm2 (A=w2t rows=D, B=h rows=S, LDK=FFF, NT=48, TPP=32)
template <int LDK, int NT, int TPP, int CPX, bool GELU>
__global__ __launch_bounds__(512, 4) void gemm_tile(
    const unsigned short* __restrict__ Abase,
    const unsigned short* __restrict__ Bbase,
    const float* __restrict__ b1,
    const int* __restrict__ topi,
    const float* __restrict__ topv,
    unsigned short* __restrict__ hout_,
    float* __restrict__ yout_) {
  int wg = (blockIdx.x & 7) * CPX + (blockIdx.x >> 3);  // XCD chunk swizzle (nwg%8==0)
  int pair = wg / TPP;
  int rem = wg - pair * TPP;
  int m0 = (rem >> 3) * 192;
  int n0 = (rem & 7) * 128;
  int e = topi[pair];
  const unsigned short* A = Abase + (size_t)e * DDIM * FFF + (size_t)m0 * LDK;
  const unsigned short* B = GELU ? Bbase + (size_t)(pair >> 1) * SS * DDIM + (size_t)n0 * LDK
                                 : Bbase + (size_t)pair * SS * FFF + (size_t)n0 * LDK;

  __shared__ unsigned short sm[40960];
  int t = threadIdx.x;
  int lane = t & 63, wave = t >> 6;
  int wm = wave >> 1, wn = wave & 1;
  int l15 = lane & 15, lg = lane >> 4, lx = lane & 7;

  // bias -> registers (keeps vmcnt ledger clean for the staging pipeline)
  f32x4 bias[3];
  float tv = 0.f;
  if constexpr (GELU) {
    int fbase = m0 + wm * 48 + lg * 4;
#pragma unroll
    for (int i = 0; i < 3; i++)
      bias[i] = *(const f32x4*)&b1[e * FFF + fbase + i * 16];
    tv = topv[pair];
  }
  asm volatile("s_waitcnt vmcnt(0)" ::: "memory");  // drain bias loads: clean ledger

  int sr = t >> 3, c4 = t & 7;
  int gch = (c4 ^ (sr & 7)) * 8;  // pre-swizzled global source (T2)
  const unsigned short* gA = A + (size_t)sr * LDK + gch;
  const unsigned short* gB = B + (size_t)sr * LDK + gch;
  unsigned short* lds_t = sm + t * 8;

#define ISSUE5(kk, so_)                                                   \
  do {                                                                    \
    async_ld16(gA + (kk), lds_t + (so_));                                 \
    async_ld16(gA + (size_t)64 * LDK + (kk), lds_t + (so_) + 4096);       \
    async_ld16(gA + (size_t)128 * LDK + (kk), lds_t + (so_) + 8192);     \
    async_ld16(gB + (kk), lds_t + (so_) + 12288);                         \
    async_ld16(gB + (size_t)64 * LDK + (kk), lds_t + (so_) + 16384);      \
  } while (0)

  ISSUE5(0, 0);
  ISSUE5(64, 20480);

  f32x4 acc[3][4];
#pragma unroll
  for (int i = 0; i < 3; i++)
#pragma unroll
    for (int j = 0; j < 4; j++) acc[i][j] = (f32x4){0.f, 0.f, 0.f, 0.f};

  int aoff = (wm * 48 + l15) * 64;
  int boff = 12288 + (wn * 64 + l15) * 64;

#define KSTEP(so_, hh)                                                               \
  do {                                                                               \
    int ch = (((hh)*4 + lg) ^ lx) * 8;                                               \
    short8 af0 = *(const short8*)&sm[(so_) + aoff + ch];                             \
    short8 af1 = *(const short8*)&sm[(so_) + aoff + 1024 + ch];                      \
    short8 af2 = *(const short8*)&sm[(so_) + aoff + 2048 + ch];                      \
    short8 bf0 = *(const short8*)&sm[(so_) + boff + ch];                             \
    short8 bf1 = *(const short8*)&sm[(so_) + boff + 1024 + ch];                      \
    short8 bf2 = *(const short8*)&sm[(so_) + boff + 2048 + ch];                      \
    short8 bf3 = *(const short8*)&sm[(so_) + boff + 3072 + ch];                      \
    acc[0][0] = __builtin_amdgcn_mfma_f32_16x16x32_bf16(af0, bf0, acc[0][0], 0, 0, 0); \
    acc[0][1] = __builtin_amdgcn_mfma_f32_16x16x32_bf16(af0, bf1, acc[0][1], 0, 0, 0); \
    acc[0][2] = __builtin_amdgcn_mfma_f32_16x16x32_bf16(af0, bf2, acc[0][2], 0, 0, 0); \
    acc[0][3] = __builtin_amdgcn_mfma_f32_16x16x32_bf16(af0, bf3, acc[0][3], 0, 0, 0); \
    acc[1][0] = __builtin_amdgcn_mfma_f32_16x16x32_bf16(af1, bf0, acc[1][0], 0, 0, 0); \
    acc[1][1] = __builtin_amdgcn_mfma_f32_16x16x32_bf16(af1, bf1, acc[1][1], 0, 0, 0); \
    acc[1][2] = __builtin_amdgcn_mfma_f32_16x16x32_bf16(af1, bf2, acc[1][2], 0, 0, 0); \
    acc[1][3] = __builtin_amdgcn_mfma_f32_16x16x32_bf16(af1, bf3, acc[1][3], 0, 0, 0); \
    acc[2][0] = __builtin_amdgcn_mfma_f32_16x16x32_bf16(af2, bf0, acc[2][0], 0, 0, 0); \
    acc[2][1] = __builtin_amdgcn_mfma_f32_16x16x32_bf16(af2, bf1, acc[2][1], 0, 0, 0); \
    acc[2][2] = __builtin_amdgcn_mfma_f32_16x16x32_bf16(af2, bf2, acc[2][2], 0, 0, 0); \
    acc[2][3] = __builtin_amdgcn_mfma_f32_16x16x32_bf16(af2, bf3, acc[2][3], 0, 0, 0); \
  } while (0)

#pragma unroll 1
  for (int kt = 0; kt < NT; kt++) {
    int so = (kt & 1) * 20480;
    if (kt == NT - 1)
      asm volatile("s_waitcnt vmcnt(0)" ::: "memory");
    else
      asm volatile("s_waitcnt vmcnt(5)" ::: "memory");
    __builtin_amdgcn_s_barrier();
    asm volatile("" ::: "memory");
    KSTEP(so, 0);
    KSTEP(so, 1);
    asm volatile("" ::: "memory");
    __builtin_amdgcn_s_barrier();
    if (kt + 2 < NT) {
      int kk = (kt + 2) * 64;
      ISSUE5(kk, so);  // stage kt+2 into the buffer just released by the barrier
    }
  }
#undef KSTEP
#undef ISSUE5

  int fb0 = m0 + wm * 48 + lg * 4;
  int sb0 = n0 + wn * 64 + l15;
  if constexpr (GELU) {
    unsigned short* ho = hout_ + (size_t)pair * SS * FFF;
#pragma unroll
    for (int j = 0; j < 4; j++) {
      int s = sb0 + j * 16;
#pragma unroll
      for (int i = 0; i < 3; i++) {
        us4 u;
#pragma unroll
        for (int r = 0; r < 4; r++) {
          float v = acc[i][j][r] + bias[i][r];
          float v2 = v * v;
          float u2 = v * (1.5957691216057308f + 0.07135481627f * v2);
          float ex = __expf(-u2);
          float g = v / (1.f + ex);
          u[r] = f2bf(g * tv);
        }
        *(us4*)&ho[(size_t)s * FFF + fb0 + i * 16] = u;
      }
    }
  } else {
    float* yo = yout_ + (size_t)pair * SS * DDIM;
#pragma unroll
    for (int j = 0; j < 4; j++) {
      int s = sb0 + j * 16;
#pragma unroll
      for (int i = 0; i < 3; i++)
        *(f32x4*)&yo[(size_t)s * DDIM + fb0 + i * 16] = acc[i][j];
    }
  }
}

// ---------------- LayerNorm + residual ----------------
__global__ void ln_kernel(const float* __restrict__ x,
                          const float* __restrict__ y,
                          const float* __restrict__ b2,
                          const int* __restrict__ topi,
                          const float* __restrict__ topv,
                          const float* __restrict__ gamma,
                          const float* __restrict__ beta,
                          float* __restrict__ out) {
  int wave = threadIdx.x >> 6, lane = threadIdx.x & 63;
  int row = blockIdx.x * 4 + wave;
  int b = row >> 10, s = row & 1023;
  int e0 = topi[b * 2], e1 = topi[b * 2 + 1];
  float tv0 = topv[b * 2], tv1 = topv[b * 2 + 1];
  const float* y0r = y + ((size_t)(b * 2) * SS + s) * DDIM;
  const float* y1r = y + ((size_t)(b * 2 + 1) * SS + s) * DDIM;
  const float* xr = x + (size_t)row * DDIM;
  float v[12];
  float sm = 0.f, s2 = 0.f;
#pragma unroll
  for (int i = 0; i < 12; i++) {
    int d = i * 64 + lane;
    float m = y0r[d] + y1r[d] + tv0 * b2[e0 * DDIM + d] + tv1 * b2[e1 * DDIM + d];
    v[i] = m; sm += m; s2 += m * m;
  }
#pragma unroll
  for (int o = 32; o > 0; o >>= 1) { sm += __shfl_xor(sm, o); s2 += __shfl_xor(s2, o); }
  float mu = sm * (1.f / DDIM);
  float var = s2 * (1.f / DDIM) - mu * mu;
  float rs = rsqrtf(var + 1e-5f);
  float* orow = out + (size_t)row * DDIM;
#pragma unroll
  for (int i = 0; i < 12; i++) {
    int d = i * 64 + lane;
    orow[d] = xr[d] + (v[i] - mu) * rs * gamma[d] + beta[d];
  }
}

extern "C" void kernel_launch(void* const* d_in, const int* in_sizes, int n_in,
                              void* d_out, int out_size, void* d_ws, size_t ws_size,
                              hipStream_t stream) {
  const float* x     = (const float*)d_in[0];
  const float* text  = (const float*)d_in[1];
  const float* W1    = (const float*)d_in[2];
  const float* b1    = (const float*)d_in[3];
  const float* W2    = (const float*)d_in[4];
  const float* b2    = (const float*)d_in[5];
  const float* rw    = (const float*)d_in[6];
  const float* rb    = (const float*)d_in[7];
  const float* gamma = (const float*)d_in[8];
  const float* beta  = (const float*)d_in[9];
  float* out   = (float*)d_out;
  float* probs = out + (size_t)BB * SS * DDIM;

  char* ws = (char*)d_ws;
  int*   topi   = (int*)ws;
  float* topv   = (float*)(ws + 256);
  float* pooled = (float*)(ws + 512);
  size_t off = 25088;
  unsigned short* xb  = (unsigned short*)(ws + off);                 // 12.58 MB
  unsigned short* w1t = (unsigned short*)(ws + off + 12582912);      // 37.75 MB
  unsigned short* w2t = w1t + (size_t)EE * DDIM * FFF;               // 37.75 MB
  unsigned short* hbuf = w2t + (size_t)EE * DDIM * FFF;              // 100.66 MB
  float* yb = (float*)(ws + off);                                    // aliases xb+w1t

  prep_kernel<<<12480, 256, 0, stream>>>(W1, W2, x, w1t, w2t, xb, pooled);
  router_kernel<<<1, 1024, 0, stream>>>(pooled, text, rw, rb, probs, topi, topv);
  // gemm1: 16 pairs x (16 M-tiles x 8 N-tiles) = 2048 blocks = 4 exact rounds @2/CU
  gemm_tile<DDIM, 12, 128, 256, true><<<2048, 512, 0, stream>>>(
      w1t, xb, b1, topi, topv, hbuf, nullptr);
  // gemm2: 16 pairs x (4 M-tiles x 8 N-tiles) = 512 blocks = 1 exact round @2/CU
  gemm_tile<FFF, 48, 32, 64, false><<<512, 512, 0, stream>>>(
      w2t, hbuf, nullptr, topi, nullptr, nullptr, yb);
  ln_kernel<<<(BB * SS) / 4, 256, 0, stream>>>(x, yb, b2, topi, topv, gamma, beta, out);
}